// Round 2
// baseline (286.135 us; speedup 1.0000x reference)
//
#include <hip/hip_runtime.h>
#include <hip/hip_bf16.h>

// DenseAttention — algebraically reassociated, all-f32 (inputs/outputs are f32
// per the reference; round-1 NaN proved the bf16-input hypothesis wrong).
//
// Reference chain (no softmax, fully linear):
//   Q    = einsum('btae,aeqf->qbtaf', x, qw)
//   pre  = einsum('qbtaf,buqf->qbtau', Q, x)          # S^2 tensor
//   attn = einsum('qbtau,buqg->abtqg', pre, x)
//   out  = einsum('abtk,akg->btag', attn, comb)
// Reassociation: attn[..q,g] = sum_f Q[..f] * G_bq[f,g],  G_bq = X_bq^T X_bq.
// Fold qw and comb into a per-(b,a) 256x256 matrix W:
//   G[b,q]   = X_bq^T X_bq                (8  x [2048x256]^T[2048x256])
//   T[b,a,q] = G[b,q] @ C[a,q]            (32 x 256^3),  C[a,q]=comb[a, q*256:, :]
//   W[b,a]   = Qw_a @ T[b,a]              (8  x [256x1024][1024x256])
//   out[b,:,a*256:] = X_ba @ W[b,a]       (8  x [2048x256][256x256])
// 6.44 GFLOP total vs 155 GFLOP for the direct form.

__device__ inline float4 load4(const float* p) { return *(const float4*)p; }

// C[m0:m0+64, n0:n0+64] = A @ B  (f32 accumulate), 256 threads, 4x4 per thread.
// AKM=false: A is [M x K] row-major (lda). AKM=true: A is [K x M] row-major (gram).
// B is [K x N] row-major (ldb). All dims multiples of 64/16 — no bounds checks.
template <bool AKM>
__device__ void gemm64(const float* __restrict__ A, int lda,
                       const float* __restrict__ B, int ldb,
                       float* __restrict__ C, int ldc,
                       int K, int m0, int n0) {
    __shared__ __align__(16) float As[16][64];  // [k][m]
    __shared__ __align__(16) float Bs[16][64];  // [k][n]
    const int tid = threadIdx.x;
    const int tx = tid & 15, ty = tid >> 4;
    float acc[4][4] = {};

    for (int k0 = 0; k0 < K; k0 += 16) {
        if (AKM) {
            const int k = tid >> 4, mq = (tid & 15) * 4;
            float4 v = load4(&A[(long)(k0 + k) * lda + m0 + mq]);
            *(float4*)&As[k][mq] = v;
        } else {
            const int m = tid >> 2, kq = (tid & 3) * 4;
            float4 v = load4(&A[(long)(m0 + m) * lda + k0 + kq]);
            As[kq + 0][m] = v.x;
            As[kq + 1][m] = v.y;
            As[kq + 2][m] = v.z;
            As[kq + 3][m] = v.w;
        }
        {
            const int k = tid >> 4, nq = (tid & 15) * 4;
            float4 v = load4(&B[(long)(k0 + k) * ldb + n0 + nq]);
            *(float4*)&Bs[k][nq] = v;
        }
        __syncthreads();
#pragma unroll
        for (int k = 0; k < 16; ++k) {
            const float4 av = *(const float4*)&As[k][ty * 4];
            const float4 bv = *(const float4*)&Bs[k][tx * 4];
            const float a[4] = {av.x, av.y, av.z, av.w};
            const float b[4] = {bv.x, bv.y, bv.z, bv.w};
#pragma unroll
            for (int i = 0; i < 4; ++i)
#pragma unroll
                for (int j = 0; j < 4; ++j)
                    acc[i][j] = fmaf(a[i], b[j], acc[i][j]);
        }
        __syncthreads();
    }
#pragma unroll
    for (int i = 0; i < 4; ++i)
#pragma unroll
        for (int j = 0; j < 4; ++j)
            C[(long)(m0 + ty * 4 + i) * ldc + n0 + tx * 4 + j] = acc[i][j];
}

// Stage 1: G[b*4+q] = X_bq^T X_bq, X_bq[u,f] = x[b, u, q*256+f] (lda 1024)
__global__ __launch_bounds__(256) void k_gram(const float* __restrict__ x,
                                              float* __restrict__ G) {
    const int tile = blockIdx.x;          // 16 tiles of 64x64 in 256x256
    const int bq = blockIdx.y;            // b*4+q
    const int b = bq >> 2, q = bq & 3;
    const float* A = x + (long)b * 2048 * 1024 + q * 256;
    float* C = G + (long)bq * 65536;
    gemm64<true>(A, 1024, A, 1024, C, 256, 2048, (tile >> 2) * 64, (tile & 3) * 64);
}

// Stage 2a: T[(b*4+a)*4+q] = G[b*4+q] @ comb[a, q*256: , :]
__global__ __launch_bounds__(256) void k_stage2a(const float* __restrict__ G,
                                                 const float* __restrict__ comb,
                                                 float* __restrict__ T) {
    const int tile = blockIdx.x;          // 16
    const int i = blockIdx.y;             // (b*4+a)*4+q, 0..31
    const int q = i & 3, ba = i >> 2;
    const int b = ba >> 2, a = ba & 3;
    const float* A = G + (long)(b * 4 + q) * 65536;
    const float* B = comb + ((long)a * 1024 + q * 256) * 256;
    float* C = T + (long)i * 65536;
    gemm64<false>(A, 256, B, 256, C, 256, 256, (tile >> 2) * 64, (tile & 3) * 64);
}

// Stage 2b: W[b*4+a] = Qw_a[256x1024] @ T[b,a][1024x256]
__global__ __launch_bounds__(256) void k_stage2b(const float* __restrict__ qw,
                                                 const float* __restrict__ T,
                                                 float* __restrict__ W) {
    const int tile = blockIdx.x;          // 16
    const int ba = blockIdx.y;            // b*4+a
    const int a = ba & 3;
    const float* A = qw + (long)a * 256 * 1024;
    const float* B = T + (long)ba * 4 * 65536;
    float* C = W + (long)ba * 65536;
    gemm64<false>(A, 1024, B, 256, C, 256, 1024, (tile >> 2) * 64, (tile & 3) * 64);
}

// Stage 3: out[b, :, a*256:] = X_ba[2048x256] @ W[b*4+a]
__global__ __launch_bounds__(256) void k_stage3(const float* __restrict__ x,
                                                const float* __restrict__ W,
                                                float* __restrict__ out) {
    const int tile = blockIdx.x;          // 128: tm 0..31, tn 0..3
    const int ba = blockIdx.y;            // b*4+a
    const int b = ba >> 2, a = ba & 3;
    const float* A = x + (long)b * 2048 * 1024 + a * 256;
    const float* B = W + (long)ba * 65536;
    float* C = out + (long)b * 2048 * 1024 + a * 256;
    gemm64<false>(A, 1024, B, 256, C, 1024, 256, (tile >> 2) * 64, (tile & 3) * 64);
}

extern "C" void kernel_launch(void* const* d_in, const int* in_sizes, int n_in,
                              void* d_out, int out_size, void* d_ws, size_t ws_size,
                              hipStream_t stream) {
    const float* x    = (const float*)d_in[0];   // [2,2048,1024] f32
    const float* qw   = (const float*)d_in[1];   // [4,256,1024]  f32
    const float* comb = (const float*)d_in[2];   // [4,1024,256]  f32
    float* out = (float*)d_out;                  // [2,2048,1024] f32

    // workspace (f32): G 2MB | T 8MB | W 2MB = 12.6 MB, fully overwritten each call
    float* G = (float*)d_ws;
    float* T = G + 8 * 65536;
    float* W = T + 32 * 65536;

    k_gram   <<<dim3(16, 8),   256, 0, stream>>>(x, G);
    k_stage2a<<<dim3(16, 32),  256, 0, stream>>>(G, comb, T);
    k_stage2b<<<dim3(16, 8),   256, 0, stream>>>(qw, T, W);
    k_stage3 <<<dim3(128, 8),  256, 0, stream>>>(x, W, out);
}

// Round 3
// 235.632 us; speedup vs baseline: 1.2143x; 1.2143x over previous
//
#include <hip/hip_runtime.h>
#include <hip/hip_bf16.h>

// DenseAttention — reassociated (6.44 GF vs 155 GF direct), all-f32.
// Round-3: fix latency-bound structure (was: 128 blocks on 256 CUs, VALUBusy 11%).
//   G[b,q]   = X_bq^T X_bq        split-K x8 -> 1024 blocks, atomicAdd into G
//   T[b,a,q] = G[b,q] @ C[a,q]    512 blocks
//   W[b,a]   = Sum_q Qw_a[:,qblk] @ T[b,a,q]   q-split x4 -> 512 blocks, atomicAdd
//   out[b,:,ablk] = X_ba @ W[b,a] 1024 blocks
// ws layout (12 MB): G f32[8][256x256] @0 | W f32[8][256x256] @2MB | T f32[32][256x256] @4MB
// G and W zeroed by one hipMemsetAsync(4MB) each call (capture-safe).

__device__ inline float4 load4(const float* p) { return *(const float4*)p; }

// C[m0:+64, n0:+64] (+)= A @ B, f32, 256 threads, 4x4/thread.
// AKM=false: A [M x K] row-major (lda). AKM=true: A [K x M] row-major (gram-style).
// B [K x N] row-major (ldb). ATOMIC: accumulate into C with atomicAdd.
template <bool AKM, bool ATOMIC>
__device__ void gemm64(const float* __restrict__ A, int lda,
                       const float* __restrict__ B, int ldb,
                       float* __restrict__ C, int ldc,
                       int K, int m0, int n0) {
    __shared__ __align__(16) float As[16][64];  // [k][m]
    __shared__ __align__(16) float Bs[16][64];  // [k][n]
    const int tid = threadIdx.x;
    const int tx = tid & 15, ty = tid >> 4;
    float acc[4][4] = {};

    for (int k0 = 0; k0 < K; k0 += 16) {
        if (AKM) {
            const int k = tid >> 4, mq = (tid & 15) * 4;
            float4 v = load4(&A[(long)(k0 + k) * lda + m0 + mq]);
            *(float4*)&As[k][mq] = v;
        } else {
            const int m = tid >> 2, kq = (tid & 3) * 4;
            float4 v = load4(&A[(long)(m0 + m) * lda + k0 + kq]);
            As[kq + 0][m] = v.x;
            As[kq + 1][m] = v.y;
            As[kq + 2][m] = v.z;
            As[kq + 3][m] = v.w;
        }
        {
            const int k = tid >> 4, nq = (tid & 15) * 4;
            float4 v = load4(&B[(long)(k0 + k) * ldb + n0 + nq]);
            *(float4*)&Bs[k][nq] = v;
        }
        __syncthreads();
#pragma unroll
        for (int k = 0; k < 16; ++k) {
            const float4 av = *(const float4*)&As[k][ty * 4];
            const float4 bv = *(const float4*)&Bs[k][tx * 4];
            const float a[4] = {av.x, av.y, av.z, av.w};
            const float b[4] = {bv.x, bv.y, bv.z, bv.w};
#pragma unroll
            for (int i = 0; i < 4; ++i)
#pragma unroll
                for (int j = 0; j < 4; ++j)
                    acc[i][j] = fmaf(a[i], b[j], acc[i][j]);
        }
        __syncthreads();
    }
#pragma unroll
    for (int i = 0; i < 4; ++i)
#pragma unroll
        for (int j = 0; j < 4; ++j) {
            float* p = &C[(long)(m0 + ty * 4 + i) * ldc + n0 + tx * 4 + j];
            if (ATOMIC) atomicAdd(p, acc[i][j]);
            else *p = acc[i][j];
        }
}

// Stage 1: G[b*4+q] += X_bq[slice]^T X_bq[slice]; grid (16 tiles, 8 bq, 8 slices)
__global__ __launch_bounds__(256) void k_gram(const float* __restrict__ x,
                                              float* __restrict__ G) {
    const int tile = blockIdx.x, bq = blockIdx.y, slice = blockIdx.z;
    const int b = bq >> 2, q = bq & 3;
    const float* A = x + (long)b * 2048 * 1024 + q * 256 + (long)slice * 256 * 1024;
    float* C = G + (long)bq * 65536;
    gemm64<true, true>(A, 1024, A, 1024, C, 256, 256, (tile >> 2) * 64, (tile & 3) * 64);
}

// Stage 2a: T[(b*4+a)*4+q] = G[b*4+q] @ comb[a, q*256:, :]; grid (16, 32)
__global__ __launch_bounds__(256) void k_stage2a(const float* __restrict__ G,
                                                 const float* __restrict__ comb,
                                                 float* __restrict__ T) {
    const int tile = blockIdx.x, i = blockIdx.y;      // i = (b*4+a)*4+q
    const int q = i & 3, ba = i >> 2;
    const int b = ba >> 2, a = ba & 3;
    const float* A = G + (long)(b * 4 + q) * 65536;
    const float* B = comb + ((long)a * 1024 + q * 256) * 256;
    float* C = T + (long)i * 65536;
    gemm64<false, false>(A, 256, B, 256, C, 256, 256, (tile >> 2) * 64, (tile & 3) * 64);
}

// Stage 2b: W[b*4+a] += Qw_a[:, q*256:+256] @ T[b,a,q]; grid (16, 8, 4)
__global__ __launch_bounds__(256) void k_stage2b(const float* __restrict__ qw,
                                                 const float* __restrict__ T,
                                                 float* __restrict__ W) {
    const int tile = blockIdx.x, ba = blockIdx.y, q = blockIdx.z;
    const int a = ba & 3;
    const float* A = qw + (long)a * 256 * 1024 + q * 256;
    const float* B = T + ((long)ba * 4 + q) * 65536;
    float* C = W + (long)ba * 65536;
    gemm64<false, true>(A, 1024, B, 256, C, 256, 256, (tile >> 2) * 64, (tile & 3) * 64);
}

// Stage 3: out[b, :, a*256:] = X_ba @ W[b*4+a]; grid (128, 8)
__global__ __launch_bounds__(256) void k_stage3(const float* __restrict__ x,
                                                const float* __restrict__ W,
                                                float* __restrict__ out) {
    const int tile = blockIdx.x, ba = blockIdx.y;
    const int b = ba >> 2, a = ba & 3;
    const float* A = x + (long)b * 2048 * 1024 + a * 256;
    const float* B = W + (long)ba * 65536;
    float* C = out + (long)b * 2048 * 1024 + a * 256;
    gemm64<false, false>(A, 1024, B, 256, C, 1024, 256, (tile >> 2) * 64, (tile & 3) * 64);
}

extern "C" void kernel_launch(void* const* d_in, const int* in_sizes, int n_in,
                              void* d_out, int out_size, void* d_ws, size_t ws_size,
                              hipStream_t stream) {
    const float* x    = (const float*)d_in[0];   // [2,2048,1024]
    const float* qw   = (const float*)d_in[1];   // [4,256,1024]
    const float* comb = (const float*)d_in[2];   // [4,1024,256]
    float* out = (float*)d_out;                  // [2,2048,1024]

    float* G = (float*)d_ws;                     // 2 MB
    float* W = G + 8 * 65536;                    // 2 MB
    float* T = G + 16 * 65536;                   // 8 MB

    hipMemsetAsync(d_ws, 0, 4u << 20, stream);   // zero G + W (atomic accumulators)

    k_gram   <<<dim3(16, 8, 8), 256, 0, stream>>>(x, G);
    k_stage2a<<<dim3(16, 32),   256, 0, stream>>>(G, comb, T);
    k_stage2b<<<dim3(16, 8, 4), 256, 0, stream>>>(qw, T, W);
    k_stage3 <<<dim3(128, 8),   256, 0, stream>>>(x, W, out);
}

// Round 4
// 168.057 us; speedup vs baseline: 1.7026x; 1.4021x over previous
//
#include <hip/hip_runtime.h>
#include <hip/hip_bf16.h>

// DenseAttention — reassociated (6.44 GF vs 155 GF direct), bf16 MFMA.
//   G[b,q]   = X_bq^T X_bq               (split-K8, atomic into f32 G)
//   Tt[ba]   = (G[b,q] @ comb[a,q*256:,:])^T stacked over q  -> [256][1024] f32
//   Wt[ba]   = (Qw_a @ T)^T              (split-K4, atomic)  -> [256][256]  f32
//   out      = X_ba @ Wt^T
// Prep pass: xt = x^T (bf16, for gram's K-major staging), qwb/combT = bf16.
// All GEMMs: 128x128 block tile, 4 waves x (64x64 = 4x4 mfma 16x16x32), BK=64.
// LDS is fragment-major: lane l's 16B frag chunk is contiguous -> conflict-free
// ds_read_b128. Verified layouts (m89/m91): A[m=lane&15][k=quad*8+j], B mirrored,
// C/D col=lane&15,row=quad*4+reg.
// ws (24 MB): G 2MB | Wt 2MB | Tt 8MB | xt 8MB | qwb 2MB | combT 2MB.

typedef unsigned short u16;
using short8  = __attribute__((ext_vector_type(8))) short;
using floatx4 = __attribute__((ext_vector_type(4))) float;

__device__ inline u16 f2bf(float f) {               // RNE f32->bf16, self-contained
    unsigned u = __float_as_uint(f);
    unsigned r = u + 0x7fffu + ((u >> 16) & 1u);
    return (u16)(r >> 16);
}

// Stage a 128-row x 64-k tile into fragment-major LDS. src points at [row0][k0].
// Element (m,k): lane = ((k&31)>>3)*16 + (m&15), j = k&7,
// chunk = ((k>>5)*8 + (m>>4))*64 + lane, ushort index = chunk*8 + j.
template <typename T>
__device__ inline void stage128(const T* __restrict__ src, long ld,
                                u16* __restrict__ dst, int tid) {
#pragma unroll
    for (int it = 0; it < 8; ++it) {
        const int flat = (it * 256 + tid) * 4;
        const int kl = flat & 63, rl = flat >> 6;
        ushort4 v;
        if (sizeof(T) == 4) {
            const float4 f = *(const float4*)&((const float*)src)[(long)rl * ld + kl];
            v.x = f2bf(f.x); v.y = f2bf(f.y); v.z = f2bf(f.z); v.w = f2bf(f.w);
        } else {
            v = *(const ushort4*)&((const u16*)src)[(long)rl * ld + kl];
        }
        const int chunk = ((kl >> 5) * 8 + (rl >> 4)) * 64 + ((kl >> 3) & 3) * 16 + (rl & 15);
        *(ushort4*)&dst[chunk * 8 + (kl & 7)] = v;
    }
}

// C[m0+.., n0+..] (+)= A @ B^T_rows. A: rows=m, cols=k (ld lda). B: rows=n, cols=k (ld ldb).
// CT: write C[n][m] instead of C[m][n]. ATOMIC: atomicAdd (split-K).
template <typename TA, typename TB, bool CT, bool ATOMIC>
__device__ inline void gemm128(const TA* __restrict__ A, long lda,
                               const TB* __restrict__ B, long ldb,
                               float* __restrict__ C, long ldc,
                               int K, int m0, int n0) {
    __shared__ u16 As[8192];   // 2 ksteps x 8 mtiles x 64 lanes x 8 bf16 = 16 KB
    __shared__ u16 Bs[8192];
    const int tid = threadIdx.x, lane = tid & 63, w = tid >> 6;
    const int IA = (w & 1) * 4, JB = (w >> 1) * 4;
    floatx4 acc[4][4] = {};

    for (int k0 = 0; k0 < K; k0 += 64) {
        stage128(A + k0, lda, As, tid);
        stage128(B + k0, ldb, Bs, tid);
        __syncthreads();
#pragma unroll
        for (int s = 0; s < 2; ++s) {
            short8 af[4], bf[4];
#pragma unroll
            for (int i = 0; i < 4; ++i)
                af[i] = *(const short8*)&As[((s * 8 + IA + i) * 64 + lane) * 8];
#pragma unroll
            for (int j = 0; j < 4; ++j)
                bf[j] = *(const short8*)&Bs[((s * 8 + JB + j) * 64 + lane) * 8];
#pragma unroll
            for (int i = 0; i < 4; ++i)
#pragma unroll
                for (int j = 0; j < 4; ++j)
                    acc[i][j] = __builtin_amdgcn_mfma_f32_16x16x32_bf16(af[i], bf[j], acc[i][j], 0, 0, 0);
        }
        __syncthreads();
    }
    const int rb = (lane >> 4) * 4, col = lane & 15;
#pragma unroll
    for (int i = 0; i < 4; ++i)
#pragma unroll
        for (int j = 0; j < 4; ++j)
#pragma unroll
            for (int r = 0; r < 4; ++r) {
                const int gm = m0 + IA * 16 + i * 16 + rb + r;
                const int gn = n0 + JB * 16 + j * 16 + col;
                float* p = CT ? &C[(long)gn * ldc + gm] : &C[(long)gm * ldc + gn];
                if (ATOMIC) atomicAdd(p, acc[i][j][r]); else *p = acc[i][j][r];
            }
}

// ---- prep: xt[b][f][u] = bf16(x[b][u][f]); qwb = bf16(qw); combT[a][n][k] = bf16(comb[a][k][n])
__device__ inline void transpose64(const float* __restrict__ src, long lds_,
                                   int r0, int c0,
                                   u16* __restrict__ dst, long ldd,
                                   float (*tile)[65], int t) {
#pragma unroll
    for (int it = 0; it < 4; ++it) {
        const int row = (t >> 4) + it * 16, cq = (t & 15) * 4;
        *(float4*)&tile[row][cq] = *(const float4*)&src[(long)(r0 + row) * lds_ + c0 + cq];
    }
    __syncthreads();
#pragma unroll
    for (int it = 0; it < 4; ++it) {
        const int cl = (t >> 4) + it * 16, rq = (t & 15) * 4;
        ushort4 v;
        v.x = f2bf(tile[rq + 0][cl]); v.y = f2bf(tile[rq + 1][cl]);
        v.z = f2bf(tile[rq + 2][cl]); v.w = f2bf(tile[rq + 3][cl]);
        *(ushort4*)&dst[(long)(c0 + cl) * ldd + r0 + rq] = v;
    }
}

__global__ __launch_bounds__(256) void k_prep(const float* __restrict__ x,
                                              const float* __restrict__ qw,
                                              const float* __restrict__ comb,
                                              u16* __restrict__ xt,
                                              u16* __restrict__ qwb,
                                              u16* __restrict__ combT) {
    __shared__ float tile[64][65];
    const int bid = blockIdx.x, t = threadIdx.x;
    if (bid < 1024) {                    // x transpose: [2048u][1024f] -> [1024f][2048u]
        const int b = bid >> 9, local = bid & 511;
        const int u0 = (local & 31) * 64, f0 = (local >> 5) * 64;
        transpose64(x + (long)b * 2097152, 1024, u0, f0, xt + (long)b * 2097152, 2048, tile, t);
    } else if (bid < 2048) {             // qw convert (layout already [m][k])
        const long off = (long)(bid - 1024) * 1024 + t * 4;
        const float4 f = *(const float4*)&qw[off];
        ushort4 v;
        v.x = f2bf(f.x); v.y = f2bf(f.y); v.z = f2bf(f.z); v.w = f2bf(f.w);
        *(ushort4*)&qwb[off] = v;
    } else {                             // comb transpose per a: [1024k][256n] -> [256n][1024k]
        const int idx = bid - 2048, a = idx >> 6, local = idx & 63;
        const int k0 = (local & 15) * 64, n0 = (local >> 4) * 64;
        transpose64(comb + (long)a * 262144, 256, k0, n0, combT + (long)a * 262144, 1024, tile, t);
    }
}

// ---- stages
__global__ __launch_bounds__(256) void k_gram(const u16* __restrict__ xt, float* __restrict__ G) {
    const int tile = blockIdx.x, bq = blockIdx.y, split = blockIdx.z;
    const int b = bq >> 2, q = bq & 3, tm = tile >> 1, tn = tile & 1;
    const u16* base = xt + (long)b * 2097152 + (long)q * 256 * 2048 + split * 256;
    gemm128<u16, u16, false, true>(base + (long)tm * 128 * 2048, 2048,
                                   base + (long)tn * 128 * 2048, 2048,
                                   G + (long)bq * 65536, 256, 256, tm * 128, tn * 128);
}

__global__ __launch_bounds__(256) void k_2a(const float* __restrict__ G,
                                            const u16* __restrict__ combT,
                                            float* __restrict__ Tt) {
    const int tile = blockIdx.x, i = blockIdx.y;
    const int q = i & 3, ba = i >> 2, b = ba >> 2, a = ba & 3;
    const int tm = tile >> 1, tn = tile & 1;
    gemm128<float, u16, true, false>(
        G + (long)(b * 4 + q) * 65536 + (long)tm * 128 * 256, 256,
        combT + (long)a * 262144 + (long)tn * 128 * 1024 + q * 256, 1024,
        Tt + (long)ba * 262144, 1024, 256, q * 256 + tm * 128, tn * 128);
}

__global__ __launch_bounds__(256) void k_2b(const u16* __restrict__ qwb,
                                            const float* __restrict__ Tt,
                                            float* __restrict__ Wt) {
    const int tile = blockIdx.x, ba = blockIdx.y, split = blockIdx.z;
    const int a = ba & 3, tm = tile >> 1, tn = tile & 1;
    gemm128<u16, float, true, true>(
        qwb + (long)a * 262144 + (long)tm * 128 * 1024 + split * 256, 1024,
        Tt + (long)ba * 262144 + (long)tn * 128 * 1024 + split * 256, 1024,
        Wt + (long)ba * 65536, 256, 256, tm * 128, tn * 128);
}

__global__ __launch_bounds__(256) void k_3(const float* __restrict__ x,
                                           const float* __restrict__ Wt,
                                           float* __restrict__ out) {
    const int tile = blockIdx.x, ba = blockIdx.y;
    const int b = ba >> 2, a = ba & 3, tm = tile >> 1, tn = tile & 1;
    gemm128<float, float, false, false>(
        x + (long)b * 2097152 + (long)tm * 128 * 1024 + a * 256, 1024,
        Wt + (long)ba * 65536 + (long)tn * 128 * 256, 256,
        out + (long)b * 2097152 + a * 256, 1024, 256, tm * 128, tn * 128);
}

extern "C" void kernel_launch(void* const* d_in, const int* in_sizes, int n_in,
                              void* d_out, int out_size, void* d_ws, size_t ws_size,
                              hipStream_t stream) {
    const float* x    = (const float*)d_in[0];   // [2,2048,1024]
    const float* qw   = (const float*)d_in[1];   // [4,256,1024]
    const float* comb = (const float*)d_in[2];   // [4,1024,256]
    float* out = (float*)d_out;

    char* ws = (char*)d_ws;
    float* G     = (float*)(ws);                 // 2 MB  [8][256x256]
    float* Wt    = (float*)(ws + (2u << 20));    // 2 MB  [8][256x256] (W^T)
    float* Tt    = (float*)(ws + (4u << 20));    // 8 MB  [8][256][1024] (T^T, q-stacked cols)
    u16*   xt    = (u16*)  (ws + (12u << 20));   // 8 MB  [2][1024][2048]
    u16*   qwb   = (u16*)  (ws + (20u << 20));   // 2 MB  [4][256][1024]
    u16*   combT = (u16*)  (ws + (22u << 20));   // 2 MB  [4][256][1024]

    hipMemsetAsync(d_ws, 0, 4u << 20, stream);   // zero G + Wt (atomic accumulators)
    k_prep<<<2304, 256, 0, stream>>>(x, qw, comb, xt, qwb, combT);
    k_gram<<<dim3(4, 8, 8), 256, 0, stream>>>(xt, G);
    k_2a  <<<dim3(4, 32),   256, 0, stream>>>(G, combT, Tt);
    k_2b  <<<dim3(4, 8, 4), 256, 0, stream>>>(qwb, Tt, Wt);
    k_3   <<<dim3(32, 8),   256, 0, stream>>>(x, Wt, out);
}